// Round 1
// baseline (416.324 us; speedup 1.0000x reference)
//
#include <hip/hip_runtime.h>

// Problem constants (fixed by setup_inputs): x (4,32,256,256) fp32, stoken=16.
// M = 0.0 -> the two appended grid channels are identically zero in both px and
// centroids, so they never affect distances or updates; drop them (C=32).
#define B_  4
#define C_  32
#define H_  256
#define W_  256
#define N_  65536   // H*W
#define NH_ 16      // superpixel grid is 16x16
#define S_  256     // nh*nw

__device__ __forceinline__ float wave_sum(float v) {
    v += __shfl_down(v, 32);
    v += __shfl_down(v, 16);
    v += __shfl_down(v, 8);
    v += __shfl_down(v, 4);
    v += __shfl_down(v, 2);
    v += __shfl_down(v, 1);
    return v;  // lane 0 holds the 64-lane sum
}

// Per-pixel softmax affinity over the 3x3 superpixel neighborhood.
// xv: the pixel's 32 channels (registers); cl[k][c]: neighbor centroids (LDS),
// garbage/zero for invalid k (masked here). Matches softmax(-dist) with
// BIG-dist for invalid, then zeroed.
__device__ __forceinline__ void compute_aff(const float xv[C_], const float (*cl)[C_],
                                            int sy, int sx, float aff[9]) {
    float dist[9];
    #pragma unroll
    for (int k = 0; k < 9; ++k) {
        const int ny = sy + k / 3 - 1, nx = sx + k % 3 - 1;
        const bool valid = (ny >= 0) & (ny < NH_) & (nx >= 0) & (nx < NH_);
        float d = 0.f;
        #pragma unroll
        for (int c = 0; c < C_; ++c) { const float df = xv[c] - cl[k][c]; d += df * df; }
        dist[k] = valid ? d : 1e30f;
    }
    float mind = dist[0];
    #pragma unroll
    for (int k = 1; k < 9; ++k) mind = fminf(mind, dist[k]);
    float sum = 0.f;
    #pragma unroll
    for (int k = 0; k < 9; ++k) {
        const float e = (dist[k] < 1e29f) ? __expf(mind - dist[k]) : 0.f;
        aff[k] = e;
        sum += e;
    }
    const float inv = 1.f / sum;   // home superpixel always valid -> sum > 0
    #pragma unroll
    for (int k = 0; k < 9; ++k) aff[k] *= inv;
}

// K1: initial centroids = mean over each 16x16 block. 1 block per (b,s).
__global__ __launch_bounds__(256) void k_cent0(const float* __restrict__ x,
                                               float* __restrict__ cent0) {
    const int blk = blockIdx.x;            // b*S_ + s
    const int b = blk >> 8, s = blk & 255;
    const int sy = s >> 4, sx = s & 15;
    const int t = threadIdx.x;
    const int w = t >> 6, lane = t & 63;
    const int py = sy * 16 + (t >> 4), pxc = sx * 16 + (t & 15);
    const float* xb = x + (size_t)b * C_ * N_ + py * W_ + pxc;
    __shared__ float acc[C_][4];
    #pragma unroll
    for (int c = 0; c < C_; ++c) {
        const float v = wave_sum(xb[c * N_]);
        if (lane == 0) acc[c][w] = v;
    }
    __syncthreads();
    if (t < C_)
        cent0[(size_t)blk * C_ + t] =
            (acc[t][0] + acc[t][1] + acc[t][2] + acc[t][3]) * (1.0f / 256.0f);
}

// K2: iteration 0 — per-pixel softmax vs cent0, scatter-accumulate num/den.
// Block = home superpixel (256 pixels). Per-wave shuffle reduction, lane0
// writes per-wave LDS slot, then <=297 global fp32 atomics per block.
__global__ __launch_bounds__(256) void k_iter0(const float* __restrict__ x,
                                               const float* __restrict__ cent0,
                                               float* __restrict__ num,
                                               float* __restrict__ den) {
    const int blk = blockIdx.x;
    const int b = blk >> 8, s = blk & 255;
    const int sy = s >> 4, sx = s & 15;
    const int t = threadIdx.x;
    const int w = t >> 6, lane = t & 63;
    __shared__ float cl[9][C_];
    __shared__ float lnum[4][9][C_];
    __shared__ float lden[4][9];
    if (t < 9 * C_) {
        const int k = t >> 5, c = t & 31;
        const int ny = sy + k / 3 - 1, nx = sx + k % 3 - 1;
        const bool valid = (ny >= 0) & (ny < NH_) & (nx >= 0) & (nx < NH_);
        cl[k][c] = valid ? cent0[(size_t)(b * S_ + ny * NH_ + nx) * C_ + c] : 0.f;
    }
    __syncthreads();
    const int py = sy * 16 + (t >> 4), pxc = sx * 16 + (t & 15);
    const float* xb = x + (size_t)b * C_ * N_ + py * W_ + pxc;
    float xv[C_];
    #pragma unroll
    for (int c = 0; c < C_; ++c) xv[c] = xb[c * N_];
    float aff[9];
    compute_aff(xv, cl, sy, sx, aff);
    #pragma unroll
    for (int k = 0; k < 9; ++k) {
        const float v = wave_sum(aff[k]);
        if (lane == 0) lden[w][k] = v;
        #pragma unroll
        for (int c = 0; c < C_; ++c) {
            const float u = wave_sum(aff[k] * xv[c]);
            if (lane == 0) lnum[w][k][c] = u;
        }
    }
    __syncthreads();
    if (t < 9 * C_) {
        const int k = t >> 5, c = t & 31;
        const int ny = sy + k / 3 - 1, nx = sx + k % 3 - 1;
        if ((ny >= 0) & (ny < NH_) & (nx >= 0) & (nx < NH_))
            unsafeAtomicAdd(&num[(size_t)(b * S_ + ny * NH_ + nx) * C_ + c],
                            lnum[0][k][c] + lnum[1][k][c] + lnum[2][k][c] + lnum[3][k][c]);
    }
    if (t < 9) {
        const int ny = sy + t / 3 - 1, nx = sx + t % 3 - 1;
        if ((ny >= 0) & (ny < NH_) & (nx >= 0) & (nx < NH_))
            unsafeAtomicAdd(&den[b * S_ + ny * NH_ + nx],
                            lden[0][t] + lden[1][t] + lden[2][t] + lden[3][t]);
    }
}

// K3: iteration 1 — cent1 = num/(den+1e-16) computed during the LDS fill;
// write compact aff9 (B,9,N). Invalid k slots get 0.
__global__ __launch_bounds__(256) void k_aff9(const float* __restrict__ x,
                                              const float* __restrict__ num,
                                              const float* __restrict__ den,
                                              float* __restrict__ aff9) {
    const int blk = blockIdx.x;
    const int b = blk >> 8, s = blk & 255;
    const int sy = s >> 4, sx = s & 15;
    const int t = threadIdx.x;
    __shared__ float cl[9][C_];
    if (t < 9 * C_) {
        const int k = t >> 5, c = t & 31;
        const int ny = sy + k / 3 - 1, nx = sx + k % 3 - 1;
        const bool valid = (ny >= 0) & (ny < NH_) & (nx >= 0) & (nx < NH_);
        if (valid) {
            const int sn = b * S_ + ny * NH_ + nx;
            cl[k][c] = num[(size_t)sn * C_ + c] / (den[sn] + 1e-16f);
        } else {
            cl[k][c] = 0.f;
        }
    }
    __syncthreads();
    const int py = sy * 16 + (t >> 4), pxc = sx * 16 + (t & 15);
    const int n = py * W_ + pxc;
    const float* xb = x + (size_t)b * C_ * N_ + n;
    float xv[C_];
    #pragma unroll
    for (int c = 0; c < C_; ++c) xv[c] = xb[c * N_];
    float aff[9];
    compute_aff(xv, cl, sy, sx, aff);
    #pragma unroll
    for (int k = 0; k < 9; ++k)
        aff9[(size_t)(b * 9 + k) * N_ + n] = aff[k];
}

// K4: dense expansion of abs_aff (B,S,N) + the scalar S output.
// One float4 per thread; out[b,s,n] = aff9[b,k,n] iff s is in pixel n's 3x3
// neighborhood (k = (sy-ly+1)*3 + (sx-lx+1)), else 0. Pure streaming writes.
__global__ __launch_bounds__(256) void k_write(const float* __restrict__ aff9,
                                               float* __restrict__ out) {
    const unsigned g = blockIdx.x * 256u + threadIdx.x;  // float4 index, < 2^24
    const int b = g >> 22;            // 256 planes * 16384 float4 each
    const int s = (g >> 14) & 255;
    const int q = g & 16383;          // float4 index within plane; n = 4q
    const int ly = q >> 10;           // (n>>8)>>4
    const int lx = (q >> 2) & 15;     // (n&255)>>4  (constant over the 4 pixels)
    const int dy = (s >> 4) - ly + 1;
    const int dx = (s & 15) - lx + 1;
    float4 v = make_float4(0.f, 0.f, 0.f, 0.f);
    if (((unsigned)dy <= 2u) & ((unsigned)dx <= 2u)) {
        const int k = dy * 3 + dx;
        v = *(const float4*)(aff9 + ((size_t)(b * 9 + k) << 16) + (q << 2));
    }
    ((float4*)out)[g] = v;
    if (g == 0) out[(size_t)B_ * S_ * N_] = 256.0f;  // second output: S = 256
}

extern "C" void kernel_launch(void* const* d_in, const int* in_sizes, int n_in,
                              void* d_out, int out_size, void* d_ws, size_t ws_size,
                              hipStream_t stream) {
    const float* x = (const float*)d_in[0];
    float* ws = (float*)d_ws;
    // ws layout (floats): cent0[32768] | num[32768] | den[1024] | aff9[2359296]
    // total ~9.7 MB. All regions fully (re)written each call (ws is poisoned).
    float* cent0 = ws;
    float* num   = ws + 32768;
    float* den   = ws + 65536;
    float* aff9  = ws + 66560;   // byte offset 266240, 16B-aligned for float4
    float* out   = (float*)d_out;

    hipMemsetAsync(num, 0, (32768 + 1024) * sizeof(float), stream);  // num+den
    hipLaunchKernelGGL(k_cent0, dim3(B_ * S_), dim3(256), 0, stream, x, cent0);
    hipLaunchKernelGGL(k_iter0, dim3(B_ * S_), dim3(256), 0, stream, x, cent0, num, den);
    hipLaunchKernelGGL(k_aff9,  dim3(B_ * S_), dim3(256), 0, stream, x, num, den, aff9);
    hipLaunchKernelGGL(k_write, dim3((B_ * S_ * N_ / 4) / 256), dim3(256), 0, stream,
                       aff9, out);
}

// Round 2
// 351.415 us; speedup vs baseline: 1.1847x; 1.1847x over previous
//
#include <hip/hip_runtime.h>

// SSN soft-superpixel assignment. Fixed shapes: x (4,32,256,256) fp32, s=16.
// M = 0 -> the two grid channels are identically zero everywhere (px and
// centroids), so they cancel in distances and updates; drop them (C=32).
#define B_  4
#define C_  32
#define H_  256
#define W_  256
#define N_  65536   // H*W
#define NH_ 16      // 16x16 superpixel grid
#define S_  256
#define PADP 260    // padded pixel stride for LDS [c][p] (4-way b128 conflicts, 1.58x)
#define PSTR 304    // per-block partial stride: 288 num + 9 den + pad (16B-mult)

__device__ __forceinline__ float wave_sum(float v) {
    v += __shfl_down(v, 32);
    v += __shfl_down(v, 16);
    v += __shfl_down(v, 8);
    v += __shfl_down(v, 4);
    v += __shfl_down(v, 2);
    v += __shfl_down(v, 1);
    return v;  // lane 0 holds the 64-lane sum
}

// Per-pixel softmax over the 3x3 superpixel neighborhood. cl[k][c] must be 0
// for invalid k (masked to aff=0 here anyway). Stable-softmax == reference
// softmax(-dist) with BIG for invalid then zeroed.
__device__ __forceinline__ void compute_aff(const float xv[C_], const float (*cl)[C_],
                                            int sy, int sx, float aff[9]) {
    float dist[9];
    #pragma unroll
    for (int k = 0; k < 9; ++k) {
        const int ny = sy + k / 3 - 1, nx = sx + k % 3 - 1;
        const bool valid = (ny >= 0) & (ny < NH_) & (nx >= 0) & (nx < NH_);
        float d = 0.f;
        #pragma unroll
        for (int c = 0; c < C_; ++c) { const float df = xv[c] - cl[k][c]; d += df * df; }
        dist[k] = valid ? d : 1e30f;
    }
    float mind = dist[0];
    #pragma unroll
    for (int k = 1; k < 9; ++k) mind = fminf(mind, dist[k]);
    float sum = 0.f;
    #pragma unroll
    for (int k = 0; k < 9; ++k) {
        const float e = (dist[k] < 1e29f) ? __expf(mind - dist[k]) : 0.f;
        aff[k] = e;
        sum += e;
    }
    const float inv = 1.f / sum;   // home superpixel always valid -> sum > 0
    #pragma unroll
    for (int k = 0; k < 9; ++k) aff[k] *= inv;
}

// K1: initial centroids = mean over each 16x16 tile. 1 block per (b,s).
__global__ __launch_bounds__(256) void k_cent0(const float* __restrict__ x,
                                               float* __restrict__ cent0) {
    const int blk = blockIdx.x;            // b*S_ + s
    const int b = blk >> 8, s = blk & 255;
    const int sy = s >> 4, sx = s & 15;
    const int t = threadIdx.x;
    const int w = t >> 6, lane = t & 63;
    const int py = sy * 16 + (t >> 4), pxc = sx * 16 + (t & 15);
    const float* xb = x + (size_t)b * C_ * N_ + py * W_ + pxc;
    __shared__ float acc[C_][4];
    #pragma unroll
    for (int c = 0; c < C_; ++c) {
        const float v = wave_sum(xb[c * N_]);
        if (lane == 0) acc[c][w] = v;
    }
    __syncthreads();
    if (t < C_)
        cent0[(size_t)blk * C_ + t] =
            (acc[t][0] + acc[t][1] + acc[t][2] + acc[t][3]) * (1.0f / 256.0f);
}

// K2: iteration 0, atomic-free. Phase A: per-pixel aff[9] vs cent0, staged to
// LDS along with x. Phase B: block partials num[k][c] = sum_p aff[k][p]*x[c][p]
// as LDS dot products (one (k,c) per thread), den[k] via 9 wave_sums.
// Partials -> part[blk][PSTR]; gathered by k_cent1 (no atomics, no memset).
__global__ __launch_bounds__(256) void k_part(const float* __restrict__ x,
                                              const float* __restrict__ cent0,
                                              float* __restrict__ part) {
    const int blk = blockIdx.x;
    const int b = blk >> 8, s = blk & 255;
    const int sy = s >> 4, sx = s & 15;
    const int t = threadIdx.x;
    const int w = t >> 6, lane = t & 63;
    __shared__ float cl[9][C_];
    __shared__ float xsh[C_][PADP];
    __shared__ float affs[9][256];
    __shared__ float lden[4][9];
    {   // fill cl: k=0..7 by all threads, k=8 by t<32 (288 entries, 256 threads)
        const int k = t >> 5, c = t & 31;
        const int ny = sy + k / 3 - 1, nx = sx + k % 3 - 1;
        const bool valid = (ny >= 0) & (ny < NH_) & (nx >= 0) & (nx < NH_);
        cl[k][c] = valid ? cent0[(size_t)(b * S_ + ny * NH_ + nx) * C_ + c] : 0.f;
    }
    if (t < 32) {
        const int ny = sy + 1, nx = sx + 1;   // k = 8
        const bool valid = (ny < NH_) & (nx < NH_);
        cl[8][t] = valid ? cent0[(size_t)(b * S_ + ny * NH_ + nx) * C_ + t] : 0.f;
    }
    __syncthreads();
    const int py = sy * 16 + (t >> 4), pxc = sx * 16 + (t & 15);
    const float* xb = x + (size_t)b * C_ * N_ + py * W_ + pxc;
    float xv[C_];
    #pragma unroll
    for (int c = 0; c < C_; ++c) { xv[c] = xb[c * N_]; xsh[c][t] = xv[c]; }
    float aff[9];
    compute_aff(xv, cl, sy, sx, aff);
    #pragma unroll
    for (int k = 0; k < 9; ++k) {
        affs[k][t] = aff[k];
        const float v = wave_sum(aff[k]);
        if (lane == 0) lden[w][k] = v;
    }
    __syncthreads();
    // Phase B: outputs t = k*32+c for k=0..7; t<32 also does k=8.
    {
        const int k = t >> 5, c = t & 31;
        float acc = 0.f;
        #pragma unroll 4
        for (int p = 0; p < 256; p += 4) {
            const float4 a = *(const float4*)&affs[k][p];     // broadcast
            const float4 xc = *(const float4*)&xsh[c][p];     // 4-way conflict
            acc += a.x * xc.x + a.y * xc.y + a.z * xc.z + a.w * xc.w;
        }
        part[(size_t)blk * PSTR + t] = acc;
    }
    if (t < 32) {
        float acc = 0.f;
        #pragma unroll 4
        for (int p = 0; p < 256; p += 4) {
            const float4 a = *(const float4*)&affs[8][p];
            const float4 xc = *(const float4*)&xsh[t][p];
            acc += a.x * xc.x + a.y * xc.y + a.z * xc.z + a.w * xc.w;
        }
        part[(size_t)blk * PSTR + 256 + t] = acc;
    }
    if (t < 9)
        part[(size_t)blk * PSTR + 288 + t] =
            lden[0][t] + lden[1][t] + lden[2][t] + lden[3][t];
}

// K3: gather partials -> cent1[b,s,c] = num/(den+1e-16). Source block for
// target s via offset k is s' = s - off(k); its k-th slot points at s.
__global__ __launch_bounds__(256) void k_cent1(const float* __restrict__ part,
                                               float* __restrict__ cent1) {
    const int g = blockIdx.x * 256 + threadIdx.x;   // < B*S*C = 32768
    const int c = g & 31, s = (g >> 5) & 255, b = g >> 13;
    const int sy = s >> 4, sx = s & 15;
    float num = 0.f, den = 0.f;
    #pragma unroll
    for (int k = 0; k < 9; ++k) {
        const int syp = sy - (k / 3 - 1), sxp = sx - (k % 3 - 1);
        if ((syp >= 0) & (syp < NH_) & (sxp >= 0) & (sxp < NH_)) {
            const size_t base = (size_t)(b * S_ + syp * NH_ + sxp) * PSTR;
            num += part[base + k * 32 + c];
            den += part[base + 288 + k];
        }
    }
    cent1[g] = num / (den + 1e-16f);
}

// K4: iteration 1 affinities vs cent1 -> compact aff9 (B,9,N).
__global__ __launch_bounds__(256) void k_aff9(const float* __restrict__ x,
                                              const float* __restrict__ cent1,
                                              float* __restrict__ aff9) {
    const int blk = blockIdx.x;
    const int b = blk >> 8, s = blk & 255;
    const int sy = s >> 4, sx = s & 15;
    const int t = threadIdx.x;
    __shared__ float cl[9][C_];
    {
        const int k = t >> 5, c = t & 31;
        const int ny = sy + k / 3 - 1, nx = sx + k % 3 - 1;
        const bool valid = (ny >= 0) & (ny < NH_) & (nx >= 0) & (nx < NH_);
        cl[k][c] = valid ? cent1[(size_t)(b * S_ + ny * NH_ + nx) * C_ + c] : 0.f;
    }
    if (t < 32) {
        const int ny = sy + 1, nx = sx + 1;   // k = 8
        const bool valid = (ny < NH_) & (nx < NH_);
        cl[8][t] = valid ? cent1[(size_t)(b * S_ + ny * NH_ + nx) * C_ + t] : 0.f;
    }
    __syncthreads();
    const int py = sy * 16 + (t >> 4), pxc = sx * 16 + (t & 15);
    const int n = py * W_ + pxc;
    const float* xb = x + (size_t)b * C_ * N_ + n;
    float xv[C_];
    #pragma unroll
    for (int c = 0; c < C_; ++c) xv[c] = xb[c * N_];
    float aff[9];
    compute_aff(xv, cl, sy, sx, aff);
    #pragma unroll
    for (int k = 0; k < 9; ++k)
        aff9[(size_t)(b * 9 + k) * N_ + n] = aff[k];
}

// K5: dense expansion (B,S,N) + scalar S. One float4/thread, pure streaming.
__global__ __launch_bounds__(256) void k_write(const float* __restrict__ aff9,
                                               float* __restrict__ out) {
    const unsigned g = blockIdx.x * 256u + threadIdx.x;  // float4 index
    const int b = g >> 22;
    const int s = (g >> 14) & 255;
    const int q = g & 16383;          // float4 index within plane; n = 4q
    const int ly = q >> 10;
    const int lx = (q >> 2) & 15;     // constant over the 4 pixels
    const int dy = (s >> 4) - ly + 1;
    const int dx = (s & 15) - lx + 1;
    float4 v = make_float4(0.f, 0.f, 0.f, 0.f);
    if (((unsigned)dy <= 2u) & ((unsigned)dx <= 2u)) {
        const int k = dy * 3 + dx;
        v = *(const float4*)(aff9 + ((size_t)(b * 9 + k) << 16) + (q << 2));
    }
    ((float4*)out)[g] = v;
    if (g == 0) out[(size_t)B_ * S_ * N_] = 256.0f;  // second output: S
}

extern "C" void kernel_launch(void* const* d_in, const int* in_sizes, int n_in,
                              void* d_out, int out_size, void* d_ws, size_t ws_size,
                              hipStream_t stream) {
    const float* x = (const float*)d_in[0];
    float* ws = (float*)d_ws;
    // ws layout (floats): cent0[32768] | part[1024*304] | cent1[32768] | aff9[2359296]
    float* cent0 = ws;
    float* part  = ws + 32768;
    float* cent1 = ws + 32768 + 1024 * PSTR;            // 344064
    float* aff9  = ws + 32768 + 1024 * PSTR + 32768;    // 376832 (16B-aligned)
    float* out   = (float*)d_out;

    hipLaunchKernelGGL(k_cent0, dim3(B_ * S_), dim3(256), 0, stream, x, cent0);
    hipLaunchKernelGGL(k_part,  dim3(B_ * S_), dim3(256), 0, stream, x, cent0, part);
    hipLaunchKernelGGL(k_cent1, dim3(B_ * S_ * C_ / 256), dim3(256), 0, stream, part, cent1);
    hipLaunchKernelGGL(k_aff9,  dim3(B_ * S_), dim3(256), 0, stream, x, cent1, aff9);
    hipLaunchKernelGGL(k_write, dim3((B_ * S_ * N_ / 4) / 256), dim3(256), 0, stream,
                       aff9, out);
}